// Round 5
// baseline (204.683 us; speedup 1.0000x reference)
//
#include <hip/hip_runtime.h>
#include <math.h>

#define NB 4
#define NH 8
#define DD 64
#define LL 2048
#define CC 64
#define QB 128
#define KB 64
#define EPS 1e-5

typedef __attribute__((ext_vector_type(4))) float f32x4;
typedef __attribute__((ext_vector_type(8))) short bf16x8;
typedef __attribute__((ext_vector_type(2))) unsigned int u32x2;
typedef __attribute__((ext_vector_type(4))) unsigned int u32x4;

// truncate two f32 to bf16 and pack into one u32 (single v_perm_b32)
__device__ __forceinline__ unsigned packtrunc(float a, float b) {
  return __builtin_amdgcn_perm(__builtin_bit_cast(unsigned, b),
                               __builtin_bit_cast(unsigned, a), 0x07060302u);
}

// block-reduce two floats, atomically add into doubles (nw waves)
__device__ __forceinline__ void reduce2_atomic(float s, float ss,
                                               double* dS, double* dSS,
                                               float* red, int nw) {
#pragma unroll
  for (int off = 32; off > 0; off >>= 1) {
    s += __shfl_xor(s, off);
    ss += __shfl_xor(ss, off);
  }
  const int t = threadIdx.x;
  if ((t & 63) == 0) { red[t >> 6] = s; red[8 + (t >> 6)] = ss; }
  __syncthreads();
  if (t == 0) {
    float S = 0.f, SS = 0.f;
    for (int w = 0; w < nw; ++w) { S += red[w]; SS += red[8 + w]; }
    atomicAdd(dS, (double)S);
    atomicAdd(dSS, (double)SS);
  }
}

// ---------- Pass 1: Gram stats, one block per bh (coalesced LDS staging) ----------
// Sigma sim^2 = Sigma_{d,d'} Gq[d,d']*Gk[d,d'];  Sigma sim = Sigma_d (Sigma_l q)(Sigma_m k)
__global__ __launch_bounds__(512, 1) void gram_kernel(
    const float* __restrict__ qg, const float* __restrict__ kg,
    double* __restrict__ ssqd, double* __restrict__ musum) {
  __shared__ short qs[64 * 256];   // [d][l-chunk] bf16, swizzled
  __shared__ short ks[64 * 256];
  __shared__ float sumbuf[128];    // [0:64]=sum_q per d, [64:128]=sum_k

  const int bh = blockIdx.x;
  const int b = bh >> 3;
  const float* qb = qg + (size_t)bh * DD * LL;
  const float* kb = kg + (size_t)bh * DD * LL;

  const int t = threadIdx.x;
  const int lane = t & 63;
  const int w = t >> 6;
  const int g = lane >> 4;
  const int ln = lane & 15;

  if (t < 128) sumbuf[t] = 0.f;

  const int d = t >> 3;            // staging row
  const int lseg = (t & 7) * 32;   // staging col segment
  const int ti = w >> 1;           // this wave's A-tile row (shared)
  const int tj0 = (w & 1) * 2;     // two B-tile cols: tj0, tj0+1

  f32x4 aq[2] = {{0.f,0.f,0.f,0.f},{0.f,0.f,0.f,0.f}};
  f32x4 ak[2] = {{0.f,0.f,0.f,0.f},{0.f,0.f,0.f,0.f}};

#pragma unroll 1
  for (int ch = 0; ch < 8; ++ch) {
    __syncthreads();   // previous compute done before overwrite
    float partq = 0.f, partk = 0.f;
    {
      const float* src = qb + (size_t)d * LL + ch * 256 + lseg;
      f32x4 v[8];
#pragma unroll
      for (int j = 0; j < 8; ++j) v[j] = *(const f32x4*)&src[j * 4];
#pragma unroll
      for (int j = 0; j < 8; ++j)
#pragma unroll
        for (int e = 0; e < 4; ++e) partq += v[j][e];
#pragma unroll
      for (int j2 = 0; j2 < 4; ++j2) {
        u32x4 wv = {packtrunc(v[2*j2][0], v[2*j2][1]), packtrunc(v[2*j2][2], v[2*j2][3]),
                    packtrunc(v[2*j2+1][0], v[2*j2+1][1]), packtrunc(v[2*j2+1][2], v[2*j2+1][3])};
        *(u32x4*)&qs[(d * 256 + lseg + j2 * 8) ^ ((d & 7) << 3)] = wv;
      }
    }
    {
      const float* src = kb + (size_t)d * LL + ch * 256 + lseg;
      f32x4 v[8];
#pragma unroll
      for (int j = 0; j < 8; ++j) v[j] = *(const f32x4*)&src[j * 4];
#pragma unroll
      for (int j = 0; j < 8; ++j)
#pragma unroll
        for (int e = 0; e < 4; ++e) partk += v[j][e];
#pragma unroll
      for (int j2 = 0; j2 < 4; ++j2) {
        u32x4 wv = {packtrunc(v[2*j2][0], v[2*j2][1]), packtrunc(v[2*j2][2], v[2*j2][3]),
                    packtrunc(v[2*j2+1][0], v[2*j2+1][1]), packtrunc(v[2*j2+1][2], v[2*j2+1][3])};
        *(u32x4*)&ks[(d * 256 + lseg + j2 * 8) ^ ((d & 7) << 3)] = wv;
      }
    }
    partq += __shfl_xor(partq, 1); partq += __shfl_xor(partq, 2); partq += __shfl_xor(partq, 4);
    partk += __shfl_xor(partk, 1); partk += __shfl_xor(partk, 2); partk += __shfl_xor(partk, 4);
    if ((t & 7) == 0) { atomicAdd(&sumbuf[d], partq); atomicAdd(&sumbuf[64 + d], partk); }
    __syncthreads();   // staging visible

#pragma unroll
    for (int kc = 0; kc < 8; ++kc) {
      const int off = kc * 32 + g * 8;
      const int sw = (ln & 7) << 3;
      const int ra = ti * 16 + ln;
      const bf16x8 faq = *(const bf16x8*)&qs[(ra * 256 + off) ^ sw];
      const bf16x8 fak = *(const bf16x8*)&ks[(ra * 256 + off) ^ sw];
      const bf16x8 fbq0 = *(const bf16x8*)&qs[((tj0 * 16 + ln) * 256 + off) ^ sw];
      const bf16x8 fbq1 = *(const bf16x8*)&qs[(((tj0 + 1) * 16 + ln) * 256 + off) ^ sw];
      const bf16x8 fbk0 = *(const bf16x8*)&ks[((tj0 * 16 + ln) * 256 + off) ^ sw];
      const bf16x8 fbk1 = *(const bf16x8*)&ks[(((tj0 + 1) * 16 + ln) * 256 + off) ^ sw];
      aq[0] = __builtin_amdgcn_mfma_f32_16x16x32_bf16(faq, fbq0, aq[0], 0, 0, 0);
      aq[1] = __builtin_amdgcn_mfma_f32_16x16x32_bf16(faq, fbq1, aq[1], 0, 0, 0);
      ak[0] = __builtin_amdgcn_mfma_f32_16x16x32_bf16(fak, fbk0, ak[0], 0, 0, 0);
      ak[1] = __builtin_amdgcn_mfma_f32_16x16x32_bf16(fak, fbk1, ak[1], 0, 0, 0);
    }
  }

  // Sigma Gq . Gk (lane-aligned element products)
  float prod = 0.f;
#pragma unroll
  for (int ip = 0; ip < 2; ++ip)
#pragma unroll
    for (int r = 0; r < 4; ++r) prod += aq[ip][r] * ak[ip][r];
#pragma unroll
  for (int off = 1; off < 64; off <<= 1) prod += __shfl_xor(prod, off);
  if (lane == 0) atomicAdd(&ssqd[b], (double)prod);

  __syncthreads();
  if (t < 64) {
    float pr = sumbuf[t] * sumbuf[64 + t];
#pragma unroll
    for (int off = 1; off < 64; off <<= 1) pr += __shfl_xor(pr, off);
    if (t == 0) atomicAdd(&musum[b], (double)pr);
  }
}

// ---------- finalize stats -> per-batch logit scale (includes log2(e)) ----------
__global__ void fin_kernel(const double* __restrict__ ssqd,
                           const double* __restrict__ musum,
                           float* __restrict__ scale2) {
  const int b = threadIdx.x;
  if (b < NB) {
    const double cnt = 33554432.0;  // NH*LL*LL
    const double mu = musum[b] / cnt;
    const double var = ssqd[b] / cnt - mu * mu;
    scale2[b] = (float)(1.4426950408889634 / sqrt(var + EPS));
  }
}

// ---------- Pass 2: flash attention, fixed-max exp2 softmax ----------
// 512 threads = 8 waves, each wave owns 16 q-rows. sc folded into staged Q.
__global__ __launch_bounds__(512, 4) void attn_kernel(
    const float* __restrict__ qg, const float* __restrict__ kg,
    const float* __restrict__ vg, float* __restrict__ rv,
    const float* __restrict__ scale2,
    double* __restrict__ s2, double* __restrict__ s2sq) {
  __shared__ short kt[KB * DD];   // [m][d] bf16, swizzle ^((m&7)<<3)
  __shared__ short vt[CC * KB];   // [c][m] bf16, swizzle ^((c&7)<<3)
  __shared__ short qp[QB * DD];   // Q [l][d] swizzled; per-wave 16-row slice reused as P
  __shared__ float red[16];

  const int phys = blockIdx.x;
  const int blk = ((phys & 7) << 6) | (phys >> 3);  // XCD-chunked, bijective
  const int lblk = blk & 15;
  const int bh = blk >> 4;
  const int b = bh >> 3;
  const int l0 = lblk * QB;

  const float* qbase = qg + (size_t)bh * DD * LL;
  const float* kbase = kg + (size_t)bh * DD * LL;
  const float* vbase = vg + (size_t)bh * CC * LL;

  const int t = threadIdx.x;
  const int lane = t & 63;
  const int wid = t >> 6;
  const int g = lane >> 4;
  const int ln = lane & 15;
  const float sc2 = scale2[b];

  // ---- stage Q tile transposed, scaled by sc2 (trunc bf16) ----
  {
    const int l = t & 127;
    const int db = (t >> 7) << 4;  // 0,16,32,48
#pragma unroll
    for (int j = 0; j < 4; ++j) {
      const int d0 = db + j * 4;
      float f0 = qbase[(size_t)(d0 + 0) * LL + l0 + l] * sc2;
      float f1 = qbase[(size_t)(d0 + 1) * LL + l0 + l] * sc2;
      float f2 = qbase[(size_t)(d0 + 2) * LL + l0 + l] * sc2;
      float f3 = qbase[(size_t)(d0 + 3) * LL + l0 + l] * sc2;
      u32x2 wq = {packtrunc(f0, f1), packtrunc(f2, f3)};
      *(u32x2*)&qp[(l * DD + d0) ^ ((l & 7) << 3)] = wq;
    }
  }
  __syncthreads();

  bf16x8 qf[2];
#pragma unroll
  for (int kc = 0; kc < 2; ++kc) {
    const int l = wid * 16 + ln;
    qf[kc] = *(const bf16x8*)&qp[(l * DD + kc * 32 + g * 8) ^ ((ln & 7) << 3)];
  }

  short* pw = qp + wid * 1024;  // wave-private P region [16][64] (own Q rows, consumed)

  f32x4 o[4];
#pragma unroll
  for (int cf = 0; cf < 4; ++cf) o[cf] = (f32x4){0.f, 0.f, 0.f, 0.f};
  f32x4 dacc = {0.f, 0.f, 0.f, 0.f};

  const unsigned one2 = 0x3F803F80u;  // two bf16 1.0
  const u32x4 onesu = {one2, one2, one2, one2};
  const bf16x8 ones = __builtin_bit_cast(bf16x8, onesu);

  float kr[2][8];
  f32x4 vr[2][2];

  auto LOADT = [&](int cur, int mt) {
    const int m0 = mt * KB;
    const int m = t & 63;
    const int d0 = (t >> 6) * 8;
#pragma unroll
    for (int j = 0; j < 8; ++j)
      kr[cur][j] = kbase[(size_t)(d0 + j) * LL + m0 + m];
    const int cb = t >> 4;          // 0..31
    const int m4 = (t & 15) * 4;
#pragma unroll
    for (int it = 0; it < 2; ++it)
      vr[cur][it] = *(const f32x4*)&vbase[(size_t)(it * 32 + cb) * LL + m0 + m4];
  };

  auto CVTW = [&](int cur) {
    const int m = t & 63;
    const int d0 = (t >> 6) * 8;
    u32x4 wk = {packtrunc(kr[cur][0], kr[cur][1]), packtrunc(kr[cur][2], kr[cur][3]),
                packtrunc(kr[cur][4], kr[cur][5]), packtrunc(kr[cur][6], kr[cur][7])};
    *(u32x4*)&kt[(m * DD + d0) ^ ((m & 7) << 3)] = wk;
    const int cb = t >> 4;
    const int m4 = (t & 15) * 4;
#pragma unroll
    for (int it = 0; it < 2; ++it) {
      const int cc = it * 32 + cb;
      f32x4 f = vr[cur][it];
      u32x2 wv = {packtrunc(f[0], f[1]), packtrunc(f[2], f[3])};
      *(u32x2*)&vt[(cc * KB + m4) ^ ((cc & 7) << 3)] = wv;
    }
  };

  auto COMPUTE = [&]() {
    f32x4 s[4];
#pragma unroll
    for (int mf = 0; mf < 4; ++mf) {
      const int m = mf * 16 + ln;
      const bf16x8 ka = *(const bf16x8*)&kt[(m * DD + g * 8) ^ ((m & 7) << 3)];
      const bf16x8 kb2 = *(const bf16x8*)&kt[(m * DD + 32 + g * 8) ^ ((m & 7) << 3)];
      f32x4 z = {0.f, 0.f, 0.f, 0.f};
      s[mf] = __builtin_amdgcn_mfma_f32_16x16x32_bf16(ka, qf[0], z, 0, 0, 0);
      s[mf] = __builtin_amdgcn_mfma_f32_16x16x32_bf16(kb2, qf[1], s[mf], 0, 0, 0);
    }
    // p = exp2(s) (sc2 already folded into Q), write bf16 P
#pragma unroll
    for (int mf = 0; mf < 4; ++mf) {
      f32x4 p;
#pragma unroll
      for (int r = 0; r < 4; ++r) p[r] = __builtin_exp2f(s[mf][r]);
      u32x2 wp = {packtrunc(p[0], p[1]), packtrunc(p[2], p[3])};
      *(u32x2*)&pw[(ln * KB + mf * 16 + g * 4) ^ ((ln & 7) << 3)] = wp;
    }
    asm volatile("s_waitcnt lgkmcnt(0)" ::: "memory");
    __builtin_amdgcn_sched_barrier(0);
    // PV + ones-column denominator
#pragma unroll
    for (int mk = 0; mk < 2; ++mk) {
      const bf16x8 pf = *(const bf16x8*)&pw[(ln * KB + mk * 32 + g * 8) ^ ((ln & 7) << 3)];
      dacc = __builtin_amdgcn_mfma_f32_16x16x32_bf16(pf, ones, dacc, 0, 0, 0);
#pragma unroll
      for (int cf = 0; cf < 4; ++cf) {
        const int c = cf * 16 + ln;
        const bf16x8 vf = *(const bf16x8*)&vt[(c * KB + mk * 32 + g * 8) ^ ((ln & 7) << 3)];
        o[cf] = __builtin_amdgcn_mfma_f32_16x16x32_bf16(pf, vf, o[cf], 0, 0, 0);
      }
    }
  };

  LOADT(0, 0);
#pragma unroll 1
  for (int mt2 = 0; mt2 < 16; ++mt2) {
    __builtin_amdgcn_s_barrier();              // all waves done reading previous tile
    asm volatile("" ::: "memory");
    CVTW(0);
    LOADT(1, mt2 * 2 + 1);
    __builtin_amdgcn_sched_barrier(0);
    asm volatile("s_waitcnt lgkmcnt(0)" ::: "memory");
    __builtin_amdgcn_s_barrier();              // staging visible
    asm volatile("" ::: "memory");
    COMPUTE();
    __builtin_amdgcn_s_barrier();
    asm volatile("" ::: "memory");
    CVTW(1);
    if (mt2 < 15) LOADT(0, mt2 * 2 + 2);
    __builtin_amdgcn_sched_barrier(0);
    asm volatile("s_waitcnt lgkmcnt(0)" ::: "memory");
    __builtin_amdgcn_s_barrier();
    asm volatile("" ::: "memory");
    COMPUTE();
  }

  // denominators are row-aligned with o (row = g*4+r)
  float inv[4];
#pragma unroll
  for (int r = 0; r < 4; ++r) inv[r] = 1.0f / dacc[r];

  float ssum = 0.f, ssq = 0.f;
  const int lout = l0 + wid * 16 + g * 4;
#pragma unroll
  for (int cf = 0; cf < 4; ++cf) {
    f32x4 ov;
#pragma unroll
    for (int r = 0; r < 4; ++r) {
      const float x = o[cf][r] * inv[r];
      ov[r] = x;
      ssum += x;
      ssq += x * x;
    }
    *(f32x4*)&rv[((size_t)(bh * CC + cf * 16 + ln)) * LL + lout] = ov;
  }
  __syncthreads();
  reduce2_atomic(ssum, ssq, &s2[b], &s2sq[b], red, 8);
}

// ---------- Pass 3: LayerNorm over (H*C, L) per batch + exact GELU ----------
__global__ __launch_bounds__(256) void ln_gelu_kernel(
    float* __restrict__ out, const double* __restrict__ s2,
    const double* __restrict__ s2sq) {
  const size_t i = ((size_t)blockIdx.x * 256 + threadIdx.x) * 4;
  const int b = (int)(i >> 20);  // H*C*L = 2^20 per batch
  const double cnt = (double)(NH * CC) * (double)LL;
  const double mean = s2[b] / cnt;
  const double var = s2sq[b] / cnt - mean * mean;
  const float invs = (float)(1.0 / sqrt(var + EPS));
  const float mu = (float)mean;
  f32x4 x = *(f32x4*)&out[i];
#pragma unroll
  for (int r = 0; r < 4; ++r) {
    const float z = (x[r] - mu) * invs;
    x[r] = 0.5f * z * (1.0f + erff(z * 0.70710678118f));
  }
  *(f32x4*)&out[i] = x;
}

extern "C" void kernel_launch(void* const* d_in, const int* in_sizes, int n_in,
                              void* d_out, int out_size, void* d_ws, size_t ws_size,
                              hipStream_t stream) {
  (void)in_sizes; (void)n_in; (void)out_size; (void)ws_size;
  const float* q = (const float*)d_in[0];
  const float* k = (const float*)d_in[1];
  const float* v = (const float*)d_in[2];
  float* out = (float*)d_out;

  double* ssqd = (double*)d_ws;      // [4]
  double* musum = ssqd + 4;          // [4]
  double* ds2 = ssqd + 8;            // [4]
  double* ds2sq = ssqd + 12;         // [4]
  float* scale2 = (float*)(ssqd + 16);  // [4]

  hipMemsetAsync(d_ws, 0, 16 * 8 + 4 * 4, stream);

  gram_kernel<<<dim3(32), dim3(512), 0, stream>>>(q, k, ssqd, musum);
  fin_kernel<<<dim3(1), dim3(64), 0, stream>>>(ssqd, musum, scale2);
  attn_kernel<<<dim3(512), dim3(512), 0, stream>>>(q, k, v, out, scale2, ds2, ds2sq);
  ln_gelu_kernel<<<dim3((NB * NH * CC * LL) / (4 * 256)), dim3(256), 0, stream>>>(out, ds2, ds2sq);
}

// Round 6
// 179.669 us; speedup vs baseline: 1.1392x; 1.1392x over previous
//
#include <hip/hip_runtime.h>
#include <math.h>

#define NB 4
#define NH 8
#define DD 64
#define LL 2048
#define CC 64
#define QB 128
#define KB 64
#define EPS 1e-5

typedef __attribute__((ext_vector_type(4))) float f32x4;
typedef __attribute__((ext_vector_type(8))) short bf16x8;
typedef __attribute__((ext_vector_type(2))) unsigned int u32x2;
typedef __attribute__((ext_vector_type(4))) unsigned int u32x4;

// truncate two f32 to bf16 and pack into one u32 (single v_perm_b32)
__device__ __forceinline__ unsigned packtrunc(float a, float b) {
  return __builtin_amdgcn_perm(__builtin_bit_cast(unsigned, b),
                               __builtin_bit_cast(unsigned, a), 0x07060302u);
}

// block-reduce two floats, atomically add into doubles (nw waves)
__device__ __forceinline__ void reduce2_atomic(float s, float ss,
                                               double* dS, double* dSS,
                                               float* red, int nw) {
#pragma unroll
  for (int off = 32; off > 0; off >>= 1) {
    s += __shfl_xor(s, off);
    ss += __shfl_xor(ss, off);
  }
  const int t = threadIdx.x;
  if ((t & 63) == 0) { red[t >> 6] = s; red[8 + (t >> 6)] = ss; }
  __syncthreads();
  if (t == 0) {
    float S = 0.f, SS = 0.f;
    for (int w = 0; w < nw; ++w) { S += red[w]; SS += red[8 + w]; }
    atomicAdd(dS, (double)S);
    atomicAdd(dSS, (double)SS);
  }
}

// ---------- Pass 1a: partial 64x64 Grams per (bh, l-chunk of 128) ----------
// grid 512 = 32 bh x 16 chunks, 256 thr. Partials -> gout (d_out scratch).
__global__ __launch_bounds__(256, 4) void gram1_kernel(
    const float* __restrict__ qg, const float* __restrict__ kg,
    float* __restrict__ gout, float* __restrict__ colq,
    float* __restrict__ colk) {
  __shared__ short qs[64 * 128];  // [d][l] bf16, swizzled
  __shared__ short ks[64 * 128];

  const int blk = blockIdx.x;
  const int bh = blk >> 4;
  const int ch = blk & 15;
  const int l0 = ch * 128;

  const float* qb = qg + (size_t)bh * DD * LL;
  const float* kb = kg + (size_t)bh * DD * LL;

  const int t = threadIdx.x;
  const int lane = t & 63;
  const int w = t >> 6;
  const int g = lane >> 4;
  const int ln = lane & 15;

  // stage: thread -> row d = t>>2, 32 l-values
  {
    const int d = t >> 2;
    const int lseg = (t & 3) * 32;
    const int swz = (d & 7) << 3;
    float pq = 0.f, pk = 0.f;
    f32x4 v[8];
#pragma unroll
    for (int j = 0; j < 8; ++j) v[j] = *(const f32x4*)&qb[(size_t)d * LL + l0 + lseg + j * 4];
#pragma unroll
    for (int j = 0; j < 8; ++j)
#pragma unroll
      for (int e = 0; e < 4; ++e) pq += v[j][e];
#pragma unroll
    for (int j2 = 0; j2 < 4; ++j2) {
      u32x4 wv = {packtrunc(v[2*j2][0], v[2*j2][1]), packtrunc(v[2*j2][2], v[2*j2][3]),
                  packtrunc(v[2*j2+1][0], v[2*j2+1][1]), packtrunc(v[2*j2+1][2], v[2*j2+1][3])};
      *(u32x4*)&qs[(d * 128 + lseg + j2 * 8) ^ swz] = wv;
    }
#pragma unroll
    for (int j = 0; j < 8; ++j) v[j] = *(const f32x4*)&kb[(size_t)d * LL + l0 + lseg + j * 4];
#pragma unroll
    for (int j = 0; j < 8; ++j)
#pragma unroll
      for (int e = 0; e < 4; ++e) pk += v[j][e];
#pragma unroll
    for (int j2 = 0; j2 < 4; ++j2) {
      u32x4 wv = {packtrunc(v[2*j2][0], v[2*j2][1]), packtrunc(v[2*j2][2], v[2*j2][3]),
                  packtrunc(v[2*j2+1][0], v[2*j2+1][1]), packtrunc(v[2*j2+1][2], v[2*j2+1][3])};
      *(u32x4*)&ks[(d * 128 + lseg + j2 * 8) ^ swz] = wv;
    }
    pq += __shfl_xor(pq, 1); pq += __shfl_xor(pq, 2);
    pk += __shfl_xor(pk, 1); pk += __shfl_xor(pk, 2);
    if ((t & 3) == 0) {
      atomicAdd(&colq[bh * DD + d], pq);
      atomicAdd(&colk[bh * DD + d], pk);
    }
  }
  __syncthreads();

  // wave w owns A-tile row ti = w; B-tiles tj = 0..3; k-dim 128 = 4 x 32
  f32x4 aq[4] = {{0,0,0,0},{0,0,0,0},{0,0,0,0},{0,0,0,0}};
  f32x4 ak[4] = {{0,0,0,0},{0,0,0,0},{0,0,0,0},{0,0,0,0}};
  const int swzl = (ln & 7) << 3;
#pragma unroll
  for (int kc = 0; kc < 4; ++kc) {
    const int off = kc * 32 + g * 8;
    const bf16x8 faq = *(const bf16x8*)&qs[((w * 16 + ln) * 128 + off) ^ swzl];
    const bf16x8 fak = *(const bf16x8*)&ks[((w * 16 + ln) * 128 + off) ^ swzl];
#pragma unroll
    for (int tj = 0; tj < 4; ++tj) {
      const bf16x8 fbq = *(const bf16x8*)&qs[((tj * 16 + ln) * 128 + off) ^ swzl];
      const bf16x8 fbk = *(const bf16x8*)&ks[((tj * 16 + ln) * 128 + off) ^ swzl];
      aq[tj] = __builtin_amdgcn_mfma_f32_16x16x32_bf16(faq, fbq, aq[tj], 0, 0, 0);
      ak[tj] = __builtin_amdgcn_mfma_f32_16x16x32_bf16(fak, fbk, ak[tj], 0, 0, 0);
    }
  }

  // write partials: gout[((bh*16+ch)*2 + tensor)*4096 + tile*256 + (g*4+r)*16 + ln]
  float* gq = gout + ((size_t)(bh * 16 + ch) * 2) * 4096;
  float* gk = gq + 4096;
#pragma unroll
  for (int tj = 0; tj < 4; ++tj) {
    const int cell = (w * 4 + tj) * 256 + g * 64 + ln;
#pragma unroll
    for (int r = 0; r < 4; ++r) {
      gq[cell + r * 16] = aq[tj][r];
      gk[cell + r * 16] = ak[tj][r];
    }
  }
}

// ---------- Pass 1b: reduce chunk partials -> Sigma Gq.Gk per batch ----------
__global__ __launch_bounds__(256, 4) void gram2_kernel(
    const float* __restrict__ gout, double* __restrict__ ssqd) {
  __shared__ float red[8];
  const int bh = blockIdx.x;
  const int t = threadIdx.x;
  const int lane = t & 63;

  const float* base = gout + (size_t)(bh * 16) * 2 * 4096;
  f32x4 sq[4] = {{0,0,0,0},{0,0,0,0},{0,0,0,0},{0,0,0,0}};
  f32x4 sk[4] = {{0,0,0,0},{0,0,0,0},{0,0,0,0},{0,0,0,0}};
#pragma unroll 1
  for (int ch = 0; ch < 16; ++ch) {
    const float* pq = base + (size_t)ch * 2 * 4096 + t * 16;
    const float* pk = pq + 4096;
#pragma unroll
    for (int i = 0; i < 4; ++i) {
      f32x4 a = *(const f32x4*)&pq[i * 4];
      f32x4 b = *(const f32x4*)&pk[i * 4];
#pragma unroll
      for (int e = 0; e < 4; ++e) { sq[i][e] += a[e]; sk[i][e] += b[e]; }
    }
  }
  float prod = 0.f;
#pragma unroll
  for (int i = 0; i < 4; ++i)
#pragma unroll
    for (int e = 0; e < 4; ++e) prod += sq[i][e] * sk[i][e];
#pragma unroll
  for (int off = 1; off < 64; off <<= 1) prod += __shfl_xor(prod, off);
  if (lane == 0) red[t >> 6] = prod;
  __syncthreads();
  if (t == 0) {
    float S = red[0] + red[1] + red[2] + red[3];
    atomicAdd(&ssqd[bh >> 3], (double)S);
  }
}

// ---------- finalize -> per-batch logit scale (includes log2(e)) ----------
__global__ void fin_kernel(const double* __restrict__ ssqd,
                           const float* __restrict__ colq,
                           const float* __restrict__ colk,
                           float* __restrict__ scale2) {
  const int t = threadIdx.x, lane = t & 63, b = t >> 6;
  float part = 0.f;
#pragma unroll
  for (int j = 0; j < 8; ++j)
    part += colq[(b * 8 + j) * DD + lane] * colk[(b * 8 + j) * DD + lane];
#pragma unroll
  for (int off = 1; off < 64; off <<= 1) part += __shfl_xor(part, off);
  if (lane == 0) {
    const double cnt = 33554432.0;  // NH*LL*LL
    const double mu = (double)part / cnt;
    const double var = ssqd[b] / cnt - mu * mu;
    scale2[b] = (float)(1.4426950408889634 / sqrt(var + EPS));
  }
}

// ---------- Pass 2: flash attention, fixed-max exp2 softmax ----------
// 256 thr = 4 waves, each wave owns 32 q-rows. K/V double-buffered, 1 barrier/tile.
__global__ __launch_bounds__(256, 2) void attn_kernel(
    const float* __restrict__ qg, const float* __restrict__ kg,
    const float* __restrict__ vg, float* __restrict__ rv,
    const float* __restrict__ scale2,
    double* __restrict__ s2, double* __restrict__ s2sq) {
  __shared__ short kt[2][KB * DD];  // [m][d] bf16, swizzle ^((m&7)<<3)
  __shared__ short vt[2][CC * KB];  // [c][m] bf16, swizzle ^((c&7)<<3)
  __shared__ short qp[QB * DD];     // Q [l][d]; per-wave 32-row slab reused as P
  __shared__ float red[16];

  const int phys = blockIdx.x;
  const int blk = ((phys & 7) << 6) | (phys >> 3);  // XCD-chunked, bijective
  const int lblk = blk & 15;
  const int bh = blk >> 4;
  const int b = bh >> 3;
  const int l0 = lblk * QB;

  const float* qbase = qg + (size_t)bh * DD * LL;
  const float* kbase = kg + (size_t)bh * DD * LL;
  const float* vbase = vg + (size_t)bh * CC * LL;

  const int t = threadIdx.x;
  const int lane = t & 63;
  const int wid = t >> 6;
  const int g = lane >> 4;
  const int ln = lane & 15;
  const float sc2 = scale2[b];

  // ---- stage Q tile transposed, scaled by sc2 (trunc bf16) ----
  {
    const int l = t & 127;
    const int db = (t >> 7) << 5;  // 0 / 32
    const int swz = (l & 7) << 3;
#pragma unroll
    for (int j2 = 0; j2 < 4; ++j2) {
      const int d0 = db + j2 * 8;
      float f[8];
#pragma unroll
      for (int j = 0; j < 8; ++j)
        f[j] = qbase[(size_t)(d0 + j) * LL + l0 + l] * sc2;
      u32x4 wq = {packtrunc(f[0], f[1]), packtrunc(f[2], f[3]),
                  packtrunc(f[4], f[5]), packtrunc(f[6], f[7])};
      *(u32x4*)&qp[(l * DD + d0) ^ swz] = wq;
    }
  }
  __syncthreads();

  bf16x8 qf[2][2];
#pragma unroll
  for (int rb = 0; rb < 2; ++rb)
#pragma unroll
    for (int kc = 0; kc < 2; ++kc) {
      const int l = wid * 32 + rb * 16 + ln;
      qf[rb][kc] = *(const bf16x8*)&qp[(l * DD + kc * 32 + g * 8) ^ ((l & 7) << 3)];
    }

  short* pw = qp + wid * 2048;  // wave-private P [32][64] (own Q rows, consumed)

  f32x4 o[2][4];
#pragma unroll
  for (int rb = 0; rb < 2; ++rb)
#pragma unroll
    for (int cf = 0; cf < 4; ++cf) o[rb][cf] = (f32x4){0.f, 0.f, 0.f, 0.f};
  f32x4 dacc[2] = {{0.f,0.f,0.f,0.f},{0.f,0.f,0.f,0.f}};

  const unsigned one2 = 0x3F803F80u;
  const u32x4 onesu = {one2, one2, one2, one2};
  const bf16x8 ones = __builtin_bit_cast(bf16x8, onesu);

  float kr[2][16];
  f32x4 vr[2][4];

  auto LOADT = [&](int cur, int mt) {
    const int m0 = mt * KB;
    const int m = t & 63;
    const int d0 = (t >> 6) * 16;
#pragma unroll
    for (int j = 0; j < 16; ++j)
      kr[cur][j] = kbase[(size_t)(d0 + j) * LL + m0 + m];
    const int c0 = t >> 4;
    const int m4 = (t & 15) * 4;
#pragma unroll
    for (int it = 0; it < 4; ++it)
      vr[cur][it] = *(const f32x4*)&vbase[(size_t)(it * 16 + c0) * LL + m0 + m4];
  };

  auto CVTW = [&](int cur) {
    const int m = t & 63;
    const int d0 = (t >> 6) * 16;
    const int swz = (m & 7) << 3;
    u32x4 w0 = {packtrunc(kr[cur][0], kr[cur][1]), packtrunc(kr[cur][2], kr[cur][3]),
                packtrunc(kr[cur][4], kr[cur][5]), packtrunc(kr[cur][6], kr[cur][7])};
    u32x4 w1 = {packtrunc(kr[cur][8], kr[cur][9]), packtrunc(kr[cur][10], kr[cur][11]),
                packtrunc(kr[cur][12], kr[cur][13]), packtrunc(kr[cur][14], kr[cur][15])};
    *(u32x4*)&kt[cur][(m * DD + d0) ^ swz] = w0;
    *(u32x4*)&kt[cur][(m * DD + d0 + 8) ^ swz] = w1;
    const int c0 = t >> 4;
    const int m4 = (t & 15) * 4;
#pragma unroll
    for (int it = 0; it < 4; ++it) {
      const int cc = it * 16 + c0;
      f32x4 f = vr[cur][it];
      u32x2 wv = {packtrunc(f[0], f[1]), packtrunc(f[2], f[3])};
      *(u32x2*)&vt[cur][(cc * KB + m4) ^ ((cc & 7) << 3)] = wv;
    }
  };

  auto COMPUTE = [&](int cur) {
    f32x4 s[2][4];
    __builtin_amdgcn_s_setprio(1);
#pragma unroll
    for (int mf = 0; mf < 4; ++mf) {
      const int m = mf * 16 + ln;
      const int swz = (m & 7) << 3;
      const bf16x8 ka = *(const bf16x8*)&kt[cur][(m * DD + g * 8) ^ swz];
      const bf16x8 kb2 = *(const bf16x8*)&kt[cur][(m * DD + 32 + g * 8) ^ swz];
      f32x4 z = {0.f, 0.f, 0.f, 0.f};
      s[0][mf] = __builtin_amdgcn_mfma_f32_16x16x32_bf16(ka, qf[0][0], z, 0, 0, 0);
      s[0][mf] = __builtin_amdgcn_mfma_f32_16x16x32_bf16(kb2, qf[0][1], s[0][mf], 0, 0, 0);
      s[1][mf] = __builtin_amdgcn_mfma_f32_16x16x32_bf16(ka, qf[1][0], z, 0, 0, 0);
      s[1][mf] = __builtin_amdgcn_mfma_f32_16x16x32_bf16(kb2, qf[1][1], s[1][mf], 0, 0, 0);
    }
    __builtin_amdgcn_s_setprio(0);
    // p = exp2(s) (sc2 folded into Q), write bf16 P to wave-private LDS
#pragma unroll
    for (int rb = 0; rb < 2; ++rb) {
      const int rr = rb * 16 + ln;
      const int swz = (rr & 7) << 3;
#pragma unroll
      for (int mf = 0; mf < 4; ++mf) {
        f32x4 p;
#pragma unroll
        for (int r = 0; r < 4; ++r) p[r] = __builtin_exp2f(s[rb][mf][r]);
        u32x2 wp = {packtrunc(p[0], p[1]), packtrunc(p[2], p[3])};
        *(u32x2*)&pw[(rr * KB + mf * 16 + g * 4) ^ swz] = wp;
      }
    }
    asm volatile("s_waitcnt lgkmcnt(0)" ::: "memory");
    __builtin_amdgcn_sched_barrier(0);
    // PV + ones-column denominator
    __builtin_amdgcn_s_setprio(1);
#pragma unroll
    for (int mk = 0; mk < 2; ++mk) {
      bf16x8 pf[2];
#pragma unroll
      for (int rb = 0; rb < 2; ++rb) {
        const int rr = rb * 16 + ln;
        pf[rb] = *(const bf16x8*)&pw[(rr * KB + mk * 32 + g * 8) ^ ((rr & 7) << 3)];
      }
      dacc[0] = __builtin_amdgcn_mfma_f32_16x16x32_bf16(pf[0], ones, dacc[0], 0, 0, 0);
      dacc[1] = __builtin_amdgcn_mfma_f32_16x16x32_bf16(pf[1], ones, dacc[1], 0, 0, 0);
#pragma unroll
      for (int cf = 0; cf < 4; ++cf) {
        const int c = cf * 16 + ln;
        const bf16x8 vf = *(const bf16x8*)&vt[cur][(c * KB + mk * 32 + g * 8) ^ ((c & 7) << 3)];
        o[0][cf] = __builtin_amdgcn_mfma_f32_16x16x32_bf16(pf[0], vf, o[0][cf], 0, 0, 0);
        o[1][cf] = __builtin_amdgcn_mfma_f32_16x16x32_bf16(pf[1], vf, o[1][cf], 0, 0, 0);
      }
    }
    __builtin_amdgcn_s_setprio(0);
  };

  // prologue: tile0 staged, tile1 in flight
  LOADT(0, 0);
  CVTW(0);
  LOADT(1, 1);
  asm volatile("s_waitcnt lgkmcnt(0)" ::: "memory");
  __builtin_amdgcn_s_barrier();
  asm volatile("" ::: "memory");

#pragma unroll 1
  for (int mt2 = 0; mt2 < 16; ++mt2) {
    const int mt = mt2 * 2;
    // even tile (buf0): stage tile mt+1 -> buf1, prefetch tile mt+2 -> regs0
    CVTW(1);
    if (mt2 < 15) LOADT(0, mt + 2);
    __builtin_amdgcn_sched_barrier(0);
    COMPUTE(0);
    asm volatile("s_waitcnt lgkmcnt(0)" ::: "memory");
    __builtin_amdgcn_s_barrier();
    asm volatile("" ::: "memory");
    // odd tile (buf1): stage tile mt+2 -> buf0, prefetch tile mt+3 -> regs1
    if (mt2 < 15) {
      CVTW(0);
      LOADT(1, mt + 3);
      __builtin_amdgcn_sched_barrier(0);
    }
    COMPUTE(1);
    asm volatile("s_waitcnt lgkmcnt(0)" ::: "memory");
    __builtin_amdgcn_s_barrier();
    asm volatile("" ::: "memory");
  }

  // normalize (dacc rows align with o rows), write rv, accumulate LN2 stats
  float ssum = 0.f, ssq = 0.f;
#pragma unroll
  for (int rb = 0; rb < 2; ++rb) {
    float inv[4];
#pragma unroll
    for (int r = 0; r < 4; ++r) inv[r] = 1.0f / dacc[rb][r];
    const int lout = l0 + wid * 32 + rb * 16 + g * 4;
#pragma unroll
    for (int cf = 0; cf < 4; ++cf) {
      f32x4 ov;
#pragma unroll
      for (int r = 0; r < 4; ++r) {
        const float x = o[rb][cf][r] * inv[r];
        ov[r] = x;
        ssum += x;
        ssq += x * x;
      }
      *(f32x4*)&rv[((size_t)(bh * CC + cf * 16 + ln)) * LL + lout] = ov;
    }
  }
  __syncthreads();
  reduce2_atomic(ssum, ssq, &s2[b], &s2sq[b], red, 4);
}

// ---------- Pass 3: LayerNorm over (H*C, L) per batch + exact GELU ----------
__global__ __launch_bounds__(256) void ln_gelu_kernel(
    float* __restrict__ out, const double* __restrict__ s2,
    const double* __restrict__ s2sq) {
  const size_t i = ((size_t)blockIdx.x * 256 + threadIdx.x) * 4;
  const int b = (int)(i >> 20);  // H*C*L = 2^20 per batch
  const double cnt = (double)(NH * CC) * (double)LL;
  const double mean = s2[b] / cnt;
  const double var = s2sq[b] / cnt - mean * mean;
  const float invs = (float)(1.0 / sqrt(var + EPS));
  const float mu = (float)mean;
  f32x4 x = *(f32x4*)&out[i];
#pragma unroll
  for (int r = 0; r < 4; ++r) {
    const float z = (x[r] - mu) * invs;
    x[r] = 0.5f * z * (1.0f + erff(z * 0.70710678118f));
  }
  *(f32x4*)&out[i] = x;
}

extern "C" void kernel_launch(void* const* d_in, const int* in_sizes, int n_in,
                              void* d_out, int out_size, void* d_ws, size_t ws_size,
                              hipStream_t stream) {
  (void)in_sizes; (void)n_in; (void)out_size; (void)ws_size;
  const float* q = (const float*)d_in[0];
  const float* k = (const float*)d_in[1];
  const float* v = (const float*)d_in[2];
  float* out = (float*)d_out;

  double* ssqd = (double*)d_ws;          // [4]
  double* ds2 = ssqd + 4;                // [4]
  double* ds2sq = ssqd + 8;              // [4]
  float* colq = (float*)(ssqd + 12);     // [32*64]
  float* colk = colq + 2048;             // [32*64]
  float* scale2 = colk + 2048;           // [4]

  hipMemsetAsync(d_ws, 0, 12 * 8 + 4096 * 4 + 4 * 4, stream);

  // gram partials use d_out as scratch (32*16*2*4096 = 4M floats = out_size);
  // attn overwrites d_out afterwards (stream-ordered).
  gram1_kernel<<<dim3(512), dim3(256), 0, stream>>>(q, k, out, colq, colk);
  gram2_kernel<<<dim3(32), dim3(256), 0, stream>>>(out, ssqd);
  fin_kernel<<<dim3(1), dim3(256), 0, stream>>>(ssqd, colq, colk, scale2);
  attn_kernel<<<dim3(512), dim3(256), 0, stream>>>(q, k, v, out, scale2, ds2, ds2sq);
  ln_gelu_kernel<<<dim3((NB * NH * CC * LL) / (4 * 256)), dim3(256), 0, stream>>>(out, ds2, ds2sq);
}